// Round 2
// baseline (366.886 us; speedup 1.0000x reference)
//
#include <hip/hip_runtime.h>
#include <hip/hip_bf16.h>
#include <stdint.h>
#include <stddef.h>

typedef unsigned short u16;
using bf16x8 = __attribute__((ext_vector_type(8))) short;   // 8 bf16 = 4 VGPR
using f32x4  = __attribute__((ext_vector_type(4))) float;

#define DEVFN static __device__ __forceinline__

DEVFN u16 f2b(float f){ __hip_bfloat16 h = __float2bfloat16(f); return *reinterpret_cast<u16*>(&h); }
DEVFN float b2f(u16 u){ __hip_bfloat16 h; *reinterpret_cast<u16*>(&h) = u; return __bfloat162float(h); }

DEVFN void gload_lds16(const void* g, void* l){
  __builtin_amdgcn_global_load_lds(
      (const __attribute__((address_space(1))) void*)g,
      (__attribute__((address_space(3))) void*)l, 16, 0, 0);
}

// ---------------- dtype detect: freqs_cos[0]==1.0f -> f32 (0x3F800000), bf16 pair -> 0x3F803F80
__global__ void detect_k(const uint32_t* __restrict__ fc_raw, uint32_t* __restrict__ flag){
  if (threadIdx.x == 0 && blockIdx.x == 0)
    flag[0] = (fc_raw[0] == 0x3F800000u) ? 1u : 0u;
}

// ---------------- freqs -> f32 table ----------------
__global__ __launch_bounds__(256) void cvtf_k(const void* __restrict__ in, float* __restrict__ out,
                                              int n, const uint32_t* __restrict__ flag){
  const int i = blockIdx.x*256 + threadIdx.x;
  if (i >= n) return;
  if (flag[0]) out[i] = ((const float*)in)[i];
  else         out[i] = b2f(((const u16*)in)[i]);
}

// ---------------- x -> bf16 (8 elems/thread) ----------------
__global__ __launch_bounds__(256) void cvtx_k(const void* __restrict__ in, u16* __restrict__ out,
                                              int n8, const uint32_t* __restrict__ flag){
  const int i = blockIdx.x*256 + threadIdx.x;
  if (i >= n8) return;
  __align__(16) u16 e[8];
  if (flag[0]){
    const float* f = (const float*)in + (size_t)i*8;
    float4 a = *(const float4*)f, b = *(const float4*)(f+4);
    e[0]=f2b(a.x); e[1]=f2b(a.y); e[2]=f2b(a.z); e[3]=f2b(a.w);
    e[4]=f2b(b.x); e[5]=f2b(b.y); e[6]=f2b(b.z); e[7]=f2b(b.w);
  } else {
    *(uint4*)e = *((const uint4*)in + i);
  }
  *(uint4*)(out + (size_t)i*8) = *(const uint4*)e;
}

// ---------------- weight transpose (+dtype cvt): in (R x C) -> out bf16 (C x R) ----------------
__global__ __launch_bounds__(512) void wtrans_k(const void* __restrict__ in, u16* __restrict__ out,
                                                int C, int R, const uint32_t* __restrict__ flag){
  __shared__ __align__(16) u16 tile[64][72];
  const int r0 = blockIdx.y*64, c0 = blockIdx.x*64;
  const int t = threadIdx.x, r = t>>3, cs = (t&7)*8;
  __align__(16) u16 e[8];
  if (flag[0]){
    const float* f = (const float*)in + (size_t)(r0+r)*C + c0 + cs;
    float4 a = *(const float4*)f, b = *(const float4*)(f+4);
    e[0]=f2b(a.x); e[1]=f2b(a.y); e[2]=f2b(a.z); e[3]=f2b(a.w);
    e[4]=f2b(b.x); e[5]=f2b(b.y); e[6]=f2b(b.z); e[7]=f2b(b.w);
  } else {
    *(uint4*)e = *(const uint4*)((const u16*)in + (size_t)(r0+r)*C + c0 + cs);
  }
#pragma unroll
  for (int j=0;j<8;j++) tile[cs+j][r] = e[j];
  __syncthreads();
  uint4 o = *(const uint4*)&tile[r][cs];
  *(uint4*)(out + (size_t)(c0+r)*R + r0 + cs) = o;
}

// ---------------- V transpose: qkv v-slice (t x d) -> vT[(b*8+g)*128 + d][t] ----------------
__global__ __launch_bounds__(512) void vtrans_k(const u16* __restrict__ qkv, u16* __restrict__ vT){
  __shared__ __align__(16) u16 tile[64][72];
  const int z = blockIdx.z, b = z>>3, g = z&7;
  const u16* in = qkv + (size_t)(b*2048)*4096 + 3072 + g*128;
  u16* out = vT + (size_t)z*128*2048;
  const int r0 = blockIdx.y*64, c0 = blockIdx.x*64;   // r0 over t, c0 over d
  const int t = threadIdx.x, r = t>>3, cs = (t&7)*8;
  uint4 v = *(const uint4*)(in + (size_t)(r0+r)*4096 + c0 + cs);
  const u16* e = (const u16*)&v;
#pragma unroll
  for (int j=0;j<8;j++) tile[cs+j][r] = e[j];
  __syncthreads();
  uint4 o = *(const uint4*)&tile[r][cs];
  *(uint4*)(out + (size_t)(c0+r)*2048 + r0 + cs) = o;
}

// ---------------- RoPE in-place on q (cols 0..2047) and k (cols 2048..3071) ----------------
__global__ __launch_bounds__(256) void rope_k(u16* qkv, const float* __restrict__ fc,
                                              const float* __restrict__ fs){
  const int idx = blockIdx.x*256 + threadIdx.x;    // 4096 rows * 1536 pairs
  const int row = idx / 1536;
  const int p   = idx % 1536;
  const int col0 = p*2;
  const int t = row & 2047;
  const int i = p & 63;
  uint32_t* ptr = (uint32_t*)(qkv + (size_t)row*4096 + col0);
  uint32_t u = *ptr;
  float x0 = b2f((u16)(u & 0xffff));
  float x1 = b2f((u16)(u >> 16));
  float c = fc[t*64+i], s = fs[t*64+i];
  float o0 = x0*c - x1*s;
  float o1 = x0*s + x1*c;
  *ptr = (uint32_t)f2b(o0) | ((uint32_t)f2b(o1) << 16);
}

// ---------------- GEMM: C(MxN) = A(MxK) * Bt(NxK)^T, bf16 in, fp32 accum ----------------
// m97 structure: 128x128 tile, BK=32, 4 waves, global_load_lds staging, LDS dbuf.
// fin/flag select final-output dtype (bf16 vs f32).
__global__ __launch_bounds__(256) void gemm_bt(const u16* __restrict__ A, const u16* __restrict__ Bt,
                                               void* __restrict__ Cv, int M, int N, int K,
                                               const uint32_t* __restrict__ flag, int fin){
  __shared__ __align__(16) u16 Al[2][128*32];
  __shared__ __align__(16) u16 Bl[2][128*32];
  const int nwg_x = N>>7;
  int wg = blockIdx.x;
  { // bijective XCD swizzle (grid % 8 == 0 for both call sites)
    const int nwg = gridDim.x;
    const int cpx = nwg >> 3;
    wg = (wg & 7)*cpx + (wg >> 3);
  }
  const int tm = (wg / nwg_x)*128, tn = (wg % nwg_x)*128;
  const int tid = threadIdx.x, w = tid>>6, l = tid&63, lr = l&15, lg = l>>4;
  const int wr = w>>1, wc = w&1;

  f32x4 acc[4][4] = {};

  auto stage = [&](int buf, int kk){
#pragma unroll
    for (int issue=0; issue<2; ++issue){
      const int c = issue*256 + w*64 + l;
      const int r = c>>2, sl = c&3;
      const int gch = sl ^ (r&3);                 // swizzled source chunk
      gload_lds16(A  + (size_t)(tm + r)*K + kk + gch*8, &Al[buf][(issue*256 + w*64)*8]);
      gload_lds16(Bt + (size_t)(tn + r)*K + kk + gch*8, &Bl[buf][(issue*256 + w*64)*8]);
    }
  };

  stage(0, 0);
  __syncthreads();
  const int nk = K>>5;
  for (int kt=0; kt<nk; ++kt){
    if (kt+1 < nk) stage((kt+1)&1, (kt+1)*32);
    const u16* Ab = Al[kt&1];
    const u16* Bb = Bl[kt&1];
    bf16x8 a[4], b[4];
#pragma unroll
    for (int mi=0;mi<4;mi++){
      const int rr = wr*64 + mi*16 + lr;
      a[mi] = *(const bf16x8*)&Ab[rr*32 + ((lg ^ (rr&3))*8)];
    }
#pragma unroll
    for (int ni=0;ni<4;ni++){
      const int rr = wc*64 + ni*16 + lr;
      b[ni] = *(const bf16x8*)&Bb[rr*32 + ((lg ^ (rr&3))*8)];
    }
#pragma unroll
    for (int mi=0;mi<4;mi++)
#pragma unroll
      for (int ni=0;ni<4;ni++)
        acc[mi][ni] = __builtin_amdgcn_mfma_f32_16x16x32_bf16(a[mi], b[ni], acc[mi][ni], 0,0,0);
    __syncthreads();
  }
  const bool of32 = fin && (flag[0] != 0);
#pragma unroll
  for (int mi=0;mi<4;mi++)
#pragma unroll
    for (int ni=0;ni<4;ni++)
#pragma unroll
      for (int reg=0;reg<4;reg++){
        const int row = tm + wr*64 + mi*16 + lg*4 + reg;
        const int col = tn + wc*64 + ni*16 + lr;
        const size_t idx = (size_t)row*N + col;
        const float v = acc[mi][ni][reg];
        if (of32) ((float*)Cv)[idx] = v;
        else      ((u16*)Cv)[idx]   = f2b(v);
      }
}

// ---------------- causal GQA flash attention ----------------
// grid (qt=16, h=16, b=2), 512 thr (8 waves). Wave w owns q rows qt*128+w*16 .. +15.
// K tile [64][128] and V^T tile [128][64] staged via global_load_lds with
// pre-swizzled global source (chunk ^= row&7); reads apply the same XOR.
__global__ __launch_bounds__(512) void attn_k(const u16* __restrict__ qkv, const u16* __restrict__ vT,
                                              u16* __restrict__ y){
  __shared__ __align__(16) u16 Kl[64*128];
  __shared__ __align__(16) u16 Vl[128*64];
  __shared__ __align__(16) u16 Pl[8][16][72];
  const int qt = blockIdx.x, h = blockIdx.y, b = blockIdx.z, g = h>>1;
  const int tid = threadIdx.x, w = tid>>6, l = tid&63, lr = l&15, lg = l>>4;
  const float scale = 0.08838834764831845f;  // 1/sqrt(128)

  const int qrowA = qt*128 + w*16 + lr;
  bf16x8 aq[4];
#pragma unroll
  for (int c=0;c<4;c++)
    aq[c] = *(const bf16x8*)(qkv + (size_t)(b*2048 + qrowA)*4096 + h*128 + c*32 + lg*8);

  f32x4 yacc[8] = {};
  float mrow[4] = {-1e30f,-1e30f,-1e30f,-1e30f};
  float lsum[4] = {0.f,0.f,0.f,0.f};
  const int qmin = qt*128 + w*16;
  const int nkt = qt*2 + 2;

  const u16* kg = qkv + (size_t)(b*2048)*4096 + 2048 + g*128;
  const u16* vg = vT  + (size_t)(b*8+g)*128*2048;

  for (int kt=0; kt<nkt; ++kt){
    const int kbase = kt*64;
#pragma unroll
    for (int issue=0; issue<2; ++issue){
      const int c = w*128 + issue*64 + l;
      { const int r = c>>4, cc = (c&15) ^ (r&7);
        gload_lds16(kg + (size_t)(kbase + r)*4096 + cc*8, &Kl[(w*128+issue*64)*8]); }
      { const int d = c>>3, cc = (c&7) ^ (d&7);
        gload_lds16(vg + (size_t)d*2048 + kbase + cc*8, &Vl[(w*128+issue*64)*8]); }
    }
    __syncthreads();

    if (kbase <= qmin + 15){          // wave-uniform causal gate
      f32x4 s[4] = {};
#pragma unroll
      for (int c=0;c<4;c++)
#pragma unroll
        for (int ng=0; ng<4; ++ng){
          const int n = ng*16 + lr;
          bf16x8 bk = *(const bf16x8*)&Kl[n*128 + (((c*4+lg) ^ (n&7))*8)];
          s[ng] = __builtin_amdgcn_mfma_f32_16x16x32_bf16(aq[c], bk, s[ng], 0,0,0);
        }
      const bool needmask = (kbase + 63) > qmin;
      float pb[4][4];      // [ng][reg]
      float corr[4];
#pragma unroll
      for (int reg=0; reg<4; ++reg){
        const int qg = qmin + lg*4 + reg;
        float vmax = -1e30f;
#pragma unroll
        for (int ng=0; ng<4; ++ng){
          float v = s[ng][reg]*scale;
          if (needmask && (kbase + ng*16 + lr) > qg) v = -1e30f;
          pb[ng][reg] = v;
          vmax = fmaxf(vmax, v);
        }
#pragma unroll
        for (int mm=1; mm<16; mm<<=1) vmax = fmaxf(vmax, __shfl_xor(vmax, mm));
        const float mnew = fmaxf(mrow[reg], vmax);
        corr[reg] = __expf(mrow[reg] - mnew);
        mrow[reg] = mnew;
        float sum = 0.f;
#pragma unroll
        for (int ng=0; ng<4; ++ng){
          const float p = __expf(pb[ng][reg] - mnew);
          pb[ng][reg] = p;
          sum += p;
        }
#pragma unroll
        for (int mm=1; mm<16; mm<<=1) sum += __shfl_xor(sum, mm);
        lsum[reg] = lsum[reg]*corr[reg] + sum;
      }
#pragma unroll
      for (int ng2=0; ng2<8; ++ng2)
#pragma unroll
        for (int reg=0; reg<4; ++reg)
          yacc[ng2][reg] *= corr[reg];
#pragma unroll
      for (int ng=0; ng<4; ++ng)
#pragma unroll
        for (int reg=0; reg<4; ++reg)
          Pl[w][lg*4+reg][ng*16+lr] = f2b(pb[ng][reg]);
      asm volatile("s_waitcnt lgkmcnt(0)" ::: "memory");
      bf16x8 ap[2];
#pragma unroll
      for (int kc=0;kc<2;kc++)
        ap[kc] = *(const bf16x8*)&Pl[w][lr][kc*32 + lg*8];
#pragma unroll
      for (int ng2=0; ng2<8; ++ng2)
#pragma unroll
        for (int kc=0; kc<2; ++kc){
          const int d = ng2*16 + lr;
          bf16x8 bv = *(const bf16x8*)&Vl[d*64 + (((kc*4+lg) ^ (d&7))*8)];
          yacc[ng2] = __builtin_amdgcn_mfma_f32_16x16x32_bf16(ap[kc], bv, yacc[ng2], 0,0,0);
        }
    }
    __syncthreads();
  }
  float inv[4];
#pragma unroll
  for (int reg=0;reg<4;reg++) inv[reg] = 1.f / lsum[reg];
#pragma unroll
  for (int ng2=0; ng2<8; ++ng2)
#pragma unroll
    for (int reg=0; reg<4; ++reg){
      const int qg = qmin + lg*4 + reg;
      y[(size_t)(b*2048 + qg)*2048 + h*128 + ng2*16 + lr] = f2b(yacc[ng2][reg]*inv[reg]);
    }
}

// ---------------- host ----------------
extern "C" void kernel_launch(void* const* d_in, const int* in_sizes, int n_in,
                              void* d_out, int out_size, void* d_ws, size_t ws_size,
                              hipStream_t stream){
  char* ws = (char*)d_ws;
  const size_t MB = 1048576;
  uint32_t* flag = (uint32_t*)(ws);
  float* fcF = (float*)(ws + 1*MB);        // 512 KB
  float* fsF = (float*)(ws + 1*MB + 524288);
  u16* xb   = (u16*)(ws + 2*MB);           // 16 MB  (reused as yb after gemm1)
  u16* waT  = (u16*)(ws + 18*MB);          // 16 MB
  u16* wpT  = (u16*)(ws + 34*MB);          // 8 MB
  u16* qkvb = (u16*)(ws + 42*MB);          // 32 MB
  u16* vTb  = (u16*)(ws + 74*MB);          // 8 MB   -> total 82 MB
  u16* yb   = xb;                          // x dead after gemm1

  detect_k<<<1, 64, 0, stream>>>((const uint32_t*)d_in[3], flag);
  cvtf_k  <<<512, 256, 0, stream>>>(d_in[3], fcF, 131072, flag);
  cvtf_k  <<<512, 256, 0, stream>>>(d_in[4], fsF, 131072, flag);
  cvtx_k  <<<4096, 256, 0, stream>>>(d_in[0], xb, 1048576, flag);
  wtrans_k<<<dim3(64,32,1), 512, 0, stream>>>(d_in[1], waT, 4096, 2048, flag);
  wtrans_k<<<dim3(32,32,1), 512, 0, stream>>>(d_in[2], wpT, 2048, 2048, flag);
  gemm_bt <<<dim3(1024,1,1), 256, 0, stream>>>(xb, waT, qkvb, 4096, 4096, 2048, flag, 0);
  rope_k  <<<dim3(24576,1,1), 256, 0, stream>>>(qkvb, fcF, fsF);
  vtrans_k<<<dim3(2,32,16), 512, 0, stream>>>(qkvb, vTb);
  attn_k  <<<dim3(16,16,2), 512, 0, stream>>>(qkvb, vTb, yb);
  gemm_bt <<<dim3(512,1,1), 256, 0, stream>>>(yb, wpT, d_out, 4096, 2048, 2048, flag, 1);
}

// Round 3
// 319.833 us; speedup vs baseline: 1.1471x; 1.1471x over previous
//
#include <hip/hip_runtime.h>
#include <hip/hip_bf16.h>
#include <stdint.h>
#include <stddef.h>

typedef unsigned short u16;
using bf16x8 = __attribute__((ext_vector_type(8))) short;   // 8 bf16 = 4 VGPR
using f32x4  = __attribute__((ext_vector_type(4))) float;

#define DEVFN static __device__ __forceinline__

DEVFN u16 f2b(float f){ __hip_bfloat16 h = __float2bfloat16(f); return *reinterpret_cast<u16*>(&h); }
DEVFN float b2f(u16 u){ __hip_bfloat16 h; *reinterpret_cast<u16*>(&h) = u; return __bfloat162float(h); }

DEVFN void gload_lds16(const void* g, void* l){
  __builtin_amdgcn_global_load_lds(
      (const __attribute__((address_space(1))) void*)g,
      (__attribute__((address_space(3))) void*)l, 16, 0, 0);
}

// ---------------- dtype detect: freqs_cos[0]==1.0f -> f32 (0x3F800000), bf16 pair -> 0x3F803F80
__global__ void detect_k(const uint32_t* __restrict__ fc_raw, uint32_t* __restrict__ flag){
  if (threadIdx.x == 0 && blockIdx.x == 0)
    flag[0] = (fc_raw[0] == 0x3F800000u) ? 1u : 0u;
}

// ---------------- freqs -> f32 table ----------------
__global__ __launch_bounds__(256) void cvtf_k(const void* __restrict__ in, float* __restrict__ out,
                                              int n, const uint32_t* __restrict__ flag){
  const int i = blockIdx.x*256 + threadIdx.x;
  if (i >= n) return;
  if (flag[0]) out[i] = ((const float*)in)[i];
  else         out[i] = b2f(((const u16*)in)[i]);
}

// ---------------- x -> bf16 (8 elems/thread) ----------------
__global__ __launch_bounds__(256) void cvtx_k(const void* __restrict__ in, u16* __restrict__ out,
                                              int n8, const uint32_t* __restrict__ flag){
  const int i = blockIdx.x*256 + threadIdx.x;
  if (i >= n8) return;
  __align__(16) u16 e[8];
  if (flag[0]){
    const float* f = (const float*)in + (size_t)i*8;
    float4 a = *(const float4*)f, b = *(const float4*)(f+4);
    e[0]=f2b(a.x); e[1]=f2b(a.y); e[2]=f2b(a.z); e[3]=f2b(a.w);
    e[4]=f2b(b.x); e[5]=f2b(b.y); e[6]=f2b(b.z); e[7]=f2b(b.w);
  } else {
    *(uint4*)e = *((const uint4*)in + i);
  }
  *(uint4*)(out + (size_t)i*8) = *(const uint4*)e;
}

// ---------------- weight transpose (+dtype cvt): in (R x C) -> out bf16 (C x R) ----------------
__global__ __launch_bounds__(512) void wtrans_k(const void* __restrict__ in, u16* __restrict__ out,
                                                int C, int R, const uint32_t* __restrict__ flag){
  __shared__ __align__(16) u16 tile[64][72];
  const int r0 = blockIdx.y*64, c0 = blockIdx.x*64;
  const int t = threadIdx.x, r = t>>3, cs = (t&7)*8;
  __align__(16) u16 e[8];
  if (flag[0]){
    const float* f = (const float*)in + (size_t)(r0+r)*C + c0 + cs;
    float4 a = *(const float4*)f, b = *(const float4*)(f+4);
    e[0]=f2b(a.x); e[1]=f2b(a.y); e[2]=f2b(a.z); e[3]=f2b(a.w);
    e[4]=f2b(b.x); e[5]=f2b(b.y); e[6]=f2b(b.z); e[7]=f2b(b.w);
  } else {
    *(uint4*)e = *(const uint4*)((const u16*)in + (size_t)(r0+r)*C + c0 + cs);
  }
#pragma unroll
  for (int j=0;j<8;j++) tile[cs+j][r] = e[j];
  __syncthreads();
  uint4 o = *(const uint4*)&tile[r][cs];
  *(uint4*)(out + (size_t)(c0+r)*R + r0 + cs) = o;
}

// ---------------- V transpose: qkv v-slice (t x d) -> vT[(b*8+g)*128 + d][t] ----------------
__global__ __launch_bounds__(512) void vtrans_k(const u16* __restrict__ qkv, u16* __restrict__ vT){
  __shared__ __align__(16) u16 tile[64][72];
  const int z = blockIdx.z, b = z>>3, g = z&7;
  const u16* in = qkv + (size_t)(b*2048)*4096 + 3072 + g*128;
  u16* out = vT + (size_t)z*128*2048;
  const int r0 = blockIdx.y*64, c0 = blockIdx.x*64;   // r0 over t, c0 over d
  const int t = threadIdx.x, r = t>>3, cs = (t&7)*8;
  uint4 v = *(const uint4*)(in + (size_t)(r0+r)*4096 + c0 + cs);
  const u16* e = (const u16*)&v;
#pragma unroll
  for (int j=0;j<8;j++) tile[cs+j][r] = e[j];
  __syncthreads();
  uint4 o = *(const uint4*)&tile[r][cs];
  *(uint4*)(out + (size_t)(c0+r)*2048 + r0 + cs) = o;
}

// ---------------- RoPE in-place on q (cols 0..2047) and k (cols 2048..3071) ----------------
__global__ __launch_bounds__(256) void rope_k(u16* qkv, const float* __restrict__ fc,
                                              const float* __restrict__ fs){
  const int idx = blockIdx.x*256 + threadIdx.x;    // 4096 rows * 1536 pairs
  const int row = idx / 1536;
  const int p   = idx % 1536;
  const int col0 = p*2;
  const int t = row & 2047;
  const int i = p & 63;
  uint32_t* ptr = (uint32_t*)(qkv + (size_t)row*4096 + col0);
  uint32_t u = *ptr;
  float x0 = b2f((u16)(u & 0xffff));
  float x1 = b2f((u16)(u >> 16));
  float c = fc[t*64+i], s = fs[t*64+i];
  float o0 = x0*c - x1*s;
  float o1 = x0*s + x1*c;
  *ptr = (uint32_t)f2b(o0) | ((uint32_t)f2b(o1) << 16);
}

// ---------------- GEMM: C(MxN) = A(MxK) * Bt(NxK)^T, bf16 in, fp32 accum ----------------
__global__ __launch_bounds__(256) void gemm_bt(const u16* __restrict__ A, const u16* __restrict__ Bt,
                                               void* __restrict__ Cv, int M, int N, int K,
                                               const uint32_t* __restrict__ flag, int fin){
  __shared__ __align__(16) u16 Al[2][128*32];
  __shared__ __align__(16) u16 Bl[2][128*32];
  const int nwg_x = N>>7;
  int wg = blockIdx.x;
  { // bijective XCD swizzle (grid % 8 == 0 for both call sites)
    const int nwg = gridDim.x;
    const int cpx = nwg >> 3;
    wg = (wg & 7)*cpx + (wg >> 3);
  }
  const int tm = (wg / nwg_x)*128, tn = (wg % nwg_x)*128;
  const int tid = threadIdx.x, w = tid>>6, l = tid&63, lr = l&15, lg = l>>4;
  const int wr = w>>1, wc = w&1;

  f32x4 acc[4][4] = {};

  auto stage = [&](int buf, int kk){
#pragma unroll
    for (int issue=0; issue<2; ++issue){
      const int c = issue*256 + w*64 + l;
      const int r = c>>2, sl = c&3;
      const int gch = sl ^ (r&3);                 // swizzled source chunk
      gload_lds16(A  + (size_t)(tm + r)*K + kk + gch*8, &Al[buf][(issue*256 + w*64)*8]);
      gload_lds16(Bt + (size_t)(tn + r)*K + kk + gch*8, &Bl[buf][(issue*256 + w*64)*8]);
    }
  };

  stage(0, 0);
  __syncthreads();
  const int nk = K>>5;
  for (int kt=0; kt<nk; ++kt){
    if (kt+1 < nk) stage((kt+1)&1, (kt+1)*32);
    const u16* Ab = Al[kt&1];
    const u16* Bb = Bl[kt&1];
    bf16x8 a[4], b[4];
#pragma unroll
    for (int mi=0;mi<4;mi++){
      const int rr = wr*64 + mi*16 + lr;
      a[mi] = *(const bf16x8*)&Ab[rr*32 + ((lg ^ (rr&3))*8)];
    }
#pragma unroll
    for (int ni=0;ni<4;ni++){
      const int rr = wc*64 + ni*16 + lr;
      b[ni] = *(const bf16x8*)&Bb[rr*32 + ((lg ^ (rr&3))*8)];
    }
#pragma unroll
    for (int mi=0;mi<4;mi++)
#pragma unroll
      for (int ni=0;ni<4;ni++)
        acc[mi][ni] = __builtin_amdgcn_mfma_f32_16x16x32_bf16(a[mi], b[ni], acc[mi][ni], 0,0,0);
    __syncthreads();
  }
  const bool of32 = fin && (flag[0] != 0);
#pragma unroll
  for (int mi=0;mi<4;mi++)
#pragma unroll
    for (int ni=0;ni<4;ni++)
#pragma unroll
      for (int reg=0;reg<4;reg++){
        const int row = tm + wr*64 + mi*16 + lg*4 + reg;
        const int col = tn + wc*64 + ni*16 + lr;
        const size_t idx = (size_t)row*N + col;
        const float v = acc[mi][ni][reg];
        if (of32) ((float*)Cv)[idx] = v;
        else      ((u16*)Cv)[idx]   = f2b(v);
      }
}

// ---------------- causal GQA flash attention ----------------
// 512 blocks, 512 thr (8 waves). Balanced remap: CU-resident pair (i, i+256)
// gets complementary qt -> every CU ~34 K-tile iters (was 4..64).
// T14 async staging: global->reg issued before compute(kt), ds_write after barrier.
__global__ __launch_bounds__(512) void attn_k(const u16* __restrict__ qkv, const u16* __restrict__ vT,
                                              u16* __restrict__ y){
  __shared__ __align__(16) u16 Kl[64*128];
  __shared__ __align__(16) u16 Vl[128*64];
  __shared__ __align__(16) u16 Pl[8][16][72];
  const int i0 = blockIdx.x;
  const int b  = i0 >> 8;                 // half
  const int h  = (i0 >> 4) & 15;
  const int vq = i0 & 15;
  const int qt = b ? (15 - vq) : vq;
  const int g  = h >> 1;
  const int tid = threadIdx.x, w = tid>>6, l = tid&63, lr = l&15, lg = l>>4;
  const float scale = 0.08838834764831845f;  // 1/sqrt(128)

  const int qrowA = qt*128 + w*16 + lr;
  bf16x8 aq[4];
#pragma unroll
  for (int c=0;c<4;c++)
    aq[c] = *(const bf16x8*)(qkv + (size_t)(b*2048 + qrowA)*4096 + h*128 + c*32 + lg*8);

  f32x4 yacc[8] = {};
  float mrow[4] = {-1e30f,-1e30f,-1e30f,-1e30f};
  float lsum[4] = {0.f,0.f,0.f,0.f};
  const int qmin = qt*128 + w*16;
  const int nkt = qt*2 + 2;

  const u16* kg = qkv + (size_t)(b*2048)*4096 + 2048 + g*128;
  const u16* vg = vT  + (size_t)(b*8+g)*128*2048;

  // staging geometry (2 chunks of K + 2 of V per thread)
  const int c0 = w*128 + l, c1 = c0 + 64;
  const int kr0 = c0>>4, kj0 = c0&15, kr1 = c1>>4, kj1 = c1&15;
  const int vd0 = c0>>3, vj0 = c0&7,  vd1 = c1>>3, vj1 = c1&7;
  u16* const kl0 = &Kl[kr0*128 + ((kj0 ^ (kr0&7))*8)];
  u16* const kl1 = &Kl[kr1*128 + ((kj1 ^ (kr1&7))*8)];
  u16* const vl0 = &Vl[vd0*64  + ((vj0 ^ (vd0&7))*8)];
  u16* const vl1 = &Vl[vd1*64  + ((vj1 ^ (vd1&7))*8)];
  uint4 kreg0, kreg1, vreg0, vreg1;
  auto loadt = [&](int kbase){
    kreg0 = *(const uint4*)(kg + (size_t)(kbase+kr0)*4096 + kj0*8);
    kreg1 = *(const uint4*)(kg + (size_t)(kbase+kr1)*4096 + kj1*8);
    vreg0 = *(const uint4*)(vg + (size_t)vd0*2048 + kbase + vj0*8);
    vreg1 = *(const uint4*)(vg + (size_t)vd1*2048 + kbase + vj1*8);
  };
  auto writet = [&](){
    *(uint4*)kl0 = kreg0; *(uint4*)kl1 = kreg1;
    *(uint4*)vl0 = vreg0; *(uint4*)vl1 = vreg1;
  };

  loadt(0);
  writet();
  __syncthreads();

  for (int kt=0; kt<nkt; ++kt){
    const int kbase = kt*64;
    if (kt+1 < nkt) loadt((kt+1)*64);   // async prefetch; __syncthreads does NOT drain reg loads (r277)

    if (kbase <= qmin + 15){            // wave-uniform causal gate
      f32x4 s[4] = {};
      __builtin_amdgcn_s_setprio(1);
#pragma unroll
      for (int c=0;c<4;c++)
#pragma unroll
        for (int ng=0; ng<4; ++ng){
          const int n = ng*16 + lr;
          bf16x8 bk = *(const bf16x8*)&Kl[n*128 + (((c*4+lg) ^ (n&7))*8)];
          s[ng] = __builtin_amdgcn_mfma_f32_16x16x32_bf16(aq[c], bk, s[ng], 0,0,0);
        }
      __builtin_amdgcn_s_setprio(0);
      const bool needmask = (kbase + 63) > qmin;
      float pb[4][4];      // [ng][reg]
      float corr[4];
#pragma unroll
      for (int reg=0; reg<4; ++reg){
        const int qg = qmin + lg*4 + reg;
        float vmax = -1e30f;
#pragma unroll
        for (int ng=0; ng<4; ++ng){
          float v = s[ng][reg]*scale;
          if (needmask && (kbase + ng*16 + lr) > qg) v = -1e30f;
          pb[ng][reg] = v;
          vmax = fmaxf(vmax, v);
        }
#pragma unroll
        for (int mm=1; mm<16; mm<<=1) vmax = fmaxf(vmax, __shfl_xor(vmax, mm));
        const float mnew = fmaxf(mrow[reg], vmax);
        corr[reg] = __expf(mrow[reg] - mnew);
        mrow[reg] = mnew;
        float sum = 0.f;
#pragma unroll
        for (int ng=0; ng<4; ++ng){
          const float p = __expf(pb[ng][reg] - mnew);
          pb[ng][reg] = p;
          sum += p;
        }
#pragma unroll
        for (int mm=1; mm<16; mm<<=1) sum += __shfl_xor(sum, mm);
        lsum[reg] = lsum[reg]*corr[reg] + sum;
      }
#pragma unroll
      for (int ng2=0; ng2<8; ++ng2)
#pragma unroll
        for (int reg=0; reg<4; ++reg)
          yacc[ng2][reg] *= corr[reg];
#pragma unroll
      for (int ng=0; ng<4; ++ng)
#pragma unroll
        for (int reg=0; reg<4; ++reg)
          Pl[w][lg*4+reg][ng*16+lr] = f2b(pb[ng][reg]);
      asm volatile("s_waitcnt lgkmcnt(0)" ::: "memory");
      bf16x8 ap[2];
#pragma unroll
      for (int kc=0;kc<2;kc++)
        ap[kc] = *(const bf16x8*)&Pl[w][lr][kc*32 + lg*8];
      __builtin_amdgcn_s_setprio(1);
#pragma unroll
      for (int ng2=0; ng2<8; ++ng2)
#pragma unroll
        for (int kc=0; kc<2; ++kc){
          const int d = ng2*16 + lr;
          bf16x8 bv = *(const bf16x8*)&Vl[d*64 + (((kc*4+lg) ^ (d&7))*8)];
          yacc[ng2] = __builtin_amdgcn_mfma_f32_16x16x32_bf16(ap[kc], bv, yacc[ng2], 0,0,0);
        }
      __builtin_amdgcn_s_setprio(0);
    }
    __syncthreads();                    // all waves done reading Kl/Vl tile kt
    if (kt+1 < nkt) writet();           // compiler waits vmcnt for kregs, then ds_write
    __syncthreads();                    // staged tile kt+1 visible
  }
  float inv[4];
#pragma unroll
  for (int reg=0;reg<4;reg++) inv[reg] = 1.f / lsum[reg];
#pragma unroll
  for (int ng2=0; ng2<8; ++ng2)
#pragma unroll
    for (int reg=0; reg<4; ++reg){
      const int qg = qmin + lg*4 + reg;
      y[(size_t)(b*2048 + qg)*2048 + h*128 + ng2*16 + lr] = f2b(yacc[ng2][reg]*inv[reg]);
    }
}

// ---------------- host ----------------
extern "C" void kernel_launch(void* const* d_in, const int* in_sizes, int n_in,
                              void* d_out, int out_size, void* d_ws, size_t ws_size,
                              hipStream_t stream){
  char* ws = (char*)d_ws;
  const size_t MB = 1048576;
  uint32_t* flag = (uint32_t*)(ws);
  float* fcF = (float*)(ws + 1*MB);        // 512 KB
  float* fsF = (float*)(ws + 1*MB + 524288);
  u16* xb   = (u16*)(ws + 2*MB);           // 16 MB  (reused as yb after gemm1)
  u16* waT  = (u16*)(ws + 18*MB);          // 16 MB
  u16* wpT  = (u16*)(ws + 34*MB);          // 8 MB
  u16* qkvb = (u16*)(ws + 42*MB);          // 32 MB
  u16* vTb  = (u16*)(ws + 74*MB);          // 8 MB   -> total 82 MB
  u16* yb   = xb;                          // x dead after gemm1

  detect_k<<<1, 64, 0, stream>>>((const uint32_t*)d_in[3], flag);
  cvtf_k  <<<512, 256, 0, stream>>>(d_in[3], fcF, 131072, flag);
  cvtf_k  <<<512, 256, 0, stream>>>(d_in[4], fsF, 131072, flag);
  cvtx_k  <<<4096, 256, 0, stream>>>(d_in[0], xb, 1048576, flag);
  wtrans_k<<<dim3(64,32,1), 512, 0, stream>>>(d_in[1], waT, 4096, 2048, flag);
  wtrans_k<<<dim3(32,32,1), 512, 0, stream>>>(d_in[2], wpT, 2048, 2048, flag);
  gemm_bt <<<dim3(1024,1,1), 256, 0, stream>>>(xb, waT, qkvb, 4096, 4096, 2048, flag, 0);
  rope_k  <<<dim3(24576,1,1), 256, 0, stream>>>(qkvb, fcF, fsF);
  vtrans_k<<<dim3(2,32,16), 512, 0, stream>>>(qkvb, vTb);
  attn_k  <<<dim3(512,1,1), 512, 0, stream>>>(qkvb, vTb, yb);
  gemm_bt <<<dim3(512,1,1), 256, 0, stream>>>(yb, wpT, d_out, 4096, 2048, 2048, flag, 1);
}

// Round 4
// 319.032 us; speedup vs baseline: 1.1500x; 1.0025x over previous
//
#include <hip/hip_runtime.h>
#include <hip/hip_bf16.h>
#include <stdint.h>
#include <stddef.h>

typedef unsigned short u16;
using bf16x8 = __attribute__((ext_vector_type(8))) short;   // 8 bf16 = 4 VGPR
using f32x4  = __attribute__((ext_vector_type(4))) float;

#define DEVFN static __device__ __forceinline__

DEVFN u16 f2b(float f){ __hip_bfloat16 h = __float2bfloat16(f); return *reinterpret_cast<u16*>(&h); }
DEVFN float b2f(u16 u){ __hip_bfloat16 h; *reinterpret_cast<u16*>(&h) = u; return __bfloat162float(h); }

DEVFN void gload_lds16(const void* g, void* l){
  __builtin_amdgcn_global_load_lds(
      (const __attribute__((address_space(1))) void*)g,
      (__attribute__((address_space(3))) void*)l, 16, 0, 0);
}

// ---------------- dtype detect: freqs_cos[0]==1.0f -> f32 (0x3F800000), bf16 pair -> 0x3F803F80
__global__ void detect_k(const uint32_t* __restrict__ fc_raw, uint32_t* __restrict__ flag){
  if (threadIdx.x == 0 && blockIdx.x == 0)
    flag[0] = (fc_raw[0] == 0x3F800000u) ? 1u : 0u;
}

// ---------------- freqs -> f32 table ----------------
__global__ __launch_bounds__(256) void cvtf_k(const void* __restrict__ in, float* __restrict__ out,
                                              int n, const uint32_t* __restrict__ flag){
  const int i = blockIdx.x*256 + threadIdx.x;
  if (i >= n) return;
  if (flag[0]) out[i] = ((const float*)in)[i];
  else         out[i] = b2f(((const u16*)in)[i]);
}

// ---------------- x -> bf16 (8 elems/thread) ----------------
__global__ __launch_bounds__(256) void cvtx_k(const void* __restrict__ in, u16* __restrict__ out,
                                              int n8, const uint32_t* __restrict__ flag){
  const int i = blockIdx.x*256 + threadIdx.x;
  if (i >= n8) return;
  __align__(16) u16 e[8];
  if (flag[0]){
    const float* f = (const float*)in + (size_t)i*8;
    float4 a = *(const float4*)f, b = *(const float4*)(f+4);
    e[0]=f2b(a.x); e[1]=f2b(a.y); e[2]=f2b(a.z); e[3]=f2b(a.w);
    e[4]=f2b(b.x); e[5]=f2b(b.y); e[6]=f2b(b.z); e[7]=f2b(b.w);
  } else {
    *(uint4*)e = *((const uint4*)in + i);
  }
  *(uint4*)(out + (size_t)i*8) = *(const uint4*)e;
}

// ---------------- weight transpose (+dtype cvt): in (R x C) -> out bf16 (C x R) ----------------
__global__ __launch_bounds__(512) void wtrans_k(const void* __restrict__ in, u16* __restrict__ out,
                                                int C, int R, const uint32_t* __restrict__ flag){
  __shared__ __align__(16) u16 tile[64][72];
  const int r0 = blockIdx.y*64, c0 = blockIdx.x*64;
  const int t = threadIdx.x, r = t>>3, cs = (t&7)*8;
  __align__(16) u16 e[8];
  if (flag[0]){
    const float* f = (const float*)in + (size_t)(r0+r)*C + c0 + cs;
    float4 a = *(const float4*)f, b = *(const float4*)(f+4);
    e[0]=f2b(a.x); e[1]=f2b(a.y); e[2]=f2b(a.z); e[3]=f2b(a.w);
    e[4]=f2b(b.x); e[5]=f2b(b.y); e[6]=f2b(b.z); e[7]=f2b(b.w);
  } else {
    *(uint4*)e = *(const uint4*)((const u16*)in + (size_t)(r0+r)*C + c0 + cs);
  }
#pragma unroll
  for (int j=0;j<8;j++) tile[cs+j][r] = e[j];
  __syncthreads();
  uint4 o = *(const uint4*)&tile[r][cs];
  *(uint4*)(out + (size_t)(c0+r)*R + r0 + cs) = o;
}

// ---------------- V transpose: qkv v-slice (t x d) -> vT[(b*8+g)*128 + d][t] ----------------
__global__ __launch_bounds__(512) void vtrans_k(const u16* __restrict__ qkv, u16* __restrict__ vT){
  __shared__ __align__(16) u16 tile[64][72];
  const int z = blockIdx.z, b = z>>3, g = z&7;
  const u16* in = qkv + (size_t)(b*2048)*4096 + 3072 + g*128;
  u16* out = vT + (size_t)z*128*2048;
  const int r0 = blockIdx.y*64, c0 = blockIdx.x*64;   // r0 over t, c0 over d
  const int t = threadIdx.x, r = t>>3, cs = (t&7)*8;
  uint4 v = *(const uint4*)(in + (size_t)(r0+r)*4096 + c0 + cs);
  const u16* e = (const u16*)&v;
#pragma unroll
  for (int j=0;j<8;j++) tile[cs+j][r] = e[j];
  __syncthreads();
  uint4 o = *(const uint4*)&tile[r][cs];
  *(uint4*)(out + (size_t)(c0+r)*2048 + r0 + cs) = o;
}

// ---------------- RoPE in-place on q (cols 0..2047) and k (cols 2048..3071) ----------------
__global__ __launch_bounds__(256) void rope_k(u16* qkv, const float* __restrict__ fc,
                                              const float* __restrict__ fs){
  const int idx = blockIdx.x*256 + threadIdx.x;    // 4096 rows * 1536 pairs
  const int row = idx / 1536;
  const int p   = idx % 1536;
  const int col0 = p*2;
  const int t = row & 2047;
  const int i = p & 63;
  uint32_t* ptr = (uint32_t*)(qkv + (size_t)row*4096 + col0);
  uint32_t u = *ptr;
  float x0 = b2f((u16)(u & 0xffff));
  float x1 = b2f((u16)(u >> 16));
  float c = fc[t*64+i], s = fs[t*64+i];
  float o0 = x0*c - x1*s;
  float o1 = x0*s + x1*c;
  *ptr = (uint32_t)f2b(o0) | ((uint32_t)f2b(o1) << 16);
}

// ---------------- GEMM: C(MxN) = A(MxK) * Bt(NxK)^T, bf16 in, fp32 accum ----------------
__global__ __launch_bounds__(256) void gemm_bt(const u16* __restrict__ A, const u16* __restrict__ Bt,
                                               void* __restrict__ Cv, int M, int N, int K,
                                               const uint32_t* __restrict__ flag, int fin){
  __shared__ __align__(16) u16 Al[2][128*32];
  __shared__ __align__(16) u16 Bl[2][128*32];
  const int nwg_x = N>>7;
  int wg = blockIdx.x;
  { // bijective XCD swizzle (grid % 8 == 0 for both call sites)
    const int nwg = gridDim.x;
    const int cpx = nwg >> 3;
    wg = (wg & 7)*cpx + (wg >> 3);
  }
  const int tm = (wg / nwg_x)*128, tn = (wg % nwg_x)*128;
  const int tid = threadIdx.x, w = tid>>6, l = tid&63, lr = l&15, lg = l>>4;
  const int wr = w>>1, wc = w&1;

  f32x4 acc[4][4] = {};

  auto stage = [&](int buf, int kk){
#pragma unroll
    for (int issue=0; issue<2; ++issue){
      const int c = issue*256 + w*64 + l;
      const int r = c>>2, sl = c&3;
      const int gch = sl ^ (r&3);                 // swizzled source chunk
      gload_lds16(A  + (size_t)(tm + r)*K + kk + gch*8, &Al[buf][(issue*256 + w*64)*8]);
      gload_lds16(Bt + (size_t)(tn + r)*K + kk + gch*8, &Bl[buf][(issue*256 + w*64)*8]);
    }
  };

  stage(0, 0);
  __syncthreads();
  const int nk = K>>5;
  for (int kt=0; kt<nk; ++kt){
    if (kt+1 < nk) stage((kt+1)&1, (kt+1)*32);
    const u16* Ab = Al[kt&1];
    const u16* Bb = Bl[kt&1];
    bf16x8 a[4], b[4];
#pragma unroll
    for (int mi=0;mi<4;mi++){
      const int rr = wr*64 + mi*16 + lr;
      a[mi] = *(const bf16x8*)&Ab[rr*32 + ((lg ^ (rr&3))*8)];
    }
#pragma unroll
    for (int ni=0;ni<4;ni++){
      const int rr = wc*64 + ni*16 + lr;
      b[ni] = *(const bf16x8*)&Bb[rr*32 + ((lg ^ (rr&3))*8)];
    }
#pragma unroll
    for (int mi=0;mi<4;mi++)
#pragma unroll
      for (int ni=0;ni<4;ni++)
        acc[mi][ni] = __builtin_amdgcn_mfma_f32_16x16x32_bf16(a[mi], b[ni], acc[mi][ni], 0,0,0);
    __syncthreads();
  }
  const bool of32 = fin && (flag[0] != 0);
#pragma unroll
  for (int mi=0;mi<4;mi++)
#pragma unroll
    for (int ni=0;ni<4;ni++)
#pragma unroll
      for (int reg=0;reg<4;reg++){
        const int row = tm + wr*64 + mi*16 + lg*4 + reg;
        const int col = tn + wc*64 + ni*16 + lr;
        const size_t idx = (size_t)row*N + col;
        const float v = acc[mi][ni][reg];
        if (of32) ((float*)Cv)[idx] = v;
        else      ((u16*)Cv)[idx]   = f2b(v);
      }
}

// ---------------- causal GQA flash attention ----------------
// 256 blocks (1/CU), 8 waves. Each block serially processes the complementary
// q-tile pair (vq, 15-vq) for one (b,h): KVBLK=128 -> (vq+1)+(16-vq) = 17
// iterations for EVERY block (scheduler-independent balance).
// Decode puts (b,g) on one XCD (K+V slice 1MB -> L2-resident).
__global__ __launch_bounds__(512) void attn_k(const u16* __restrict__ qkv, const u16* __restrict__ vT,
                                              u16* __restrict__ y){
  __shared__ __align__(16) u16 Kl[128*128];      // 32KB  [krow][chunk^(krow&15)]
  __shared__ __align__(16) u16 Vl[128*128];      // 32KB  [d][chunk^(d&15)]
  __shared__ __align__(16) u16 Pl[8][16][132];   // 33.8KB, stride 132 -> conflict-free
  const int i0 = blockIdx.x;
  const int g  = i0 & 7;                  // XCD-local (b,g) slice
  const int s  = i0 >> 3;                 // 0..31
  const int b  = s >> 4;
  const int h  = g*2 + (s & 1);
  const int vq = (s >> 1) & 7;
  const int tid = threadIdx.x, w = tid>>6, l = tid&63, lr = l&15, lg = l>>4;
  const float scale = 0.08838834764831845f;  // 1/sqrt(128)

  const u16* kg = qkv + (size_t)(b*2048)*4096 + 2048 + g*128;
  const u16* vg = vT  + (size_t)(b*8+g)*128*2048;

  // staging geometry: thread covers K row rk (chunks (tid&3)+4j) and V row rk
  const int rk = tid >> 2;                // 0..127
  const int cb = tid & 3;
  u16* klp[4]; u16* vlp[4];
#pragma unroll
  for (int j=0;j<4;j++){
    const int ch = cb + j*4;
    klp[j] = &Kl[rk*128 + ((ch ^ (rk&15))*8)];
    vlp[j] = &Vl[rk*128 + ((ch ^ (rk&15))*8)];
  }
  uint4 kpre[4], vpre[4];

  const int nA = vq + 1;                  // iters in phase A (qt=vq); total 17
  auto loadt = [&](int it){
    const int kb = ((it < nA) ? it : it - nA) * 128;
#pragma unroll
    for (int j=0;j<4;j++){
      kpre[j] = *(const uint4*)(kg + (size_t)(kb + rk)*4096 + (cb + j*4)*8);
      vpre[j] = *(const uint4*)(vg + (size_t)rk*2048 + kb + (cb + j*4)*8);
    }
  };
  auto writet = [&](){
#pragma unroll
    for (int j=0;j<4;j++){ *(uint4*)klp[j] = kpre[j]; *(uint4*)vlp[j] = vpre[j]; }
  };

  loadt(0); writet(); __syncthreads();

  bf16x8 aq[4];
  f32x4 yacc[8];
  float mrow[4], lsum[4];
  int qt = vq;
  auto loadQ = [&](){
    const size_t qrow = (size_t)(b*2048 + qt*128 + w*16 + lr);
#pragma unroll
    for (int c=0;c<4;c++)
      aq[c] = *(const bf16x8*)(qkv + qrow*4096 + h*128 + c*32 + lg*8);
  };
  auto resetAcc = [&](){
#pragma unroll
    for (int n=0;n<8;n++) yacc[n] = f32x4{0.f,0.f,0.f,0.f};
#pragma unroll
    for (int r=0;r<4;r++){ mrow[r] = -1e30f; lsum[r] = 0.f; }
  };
  auto writeOut = [&](){
    float inv[4];
#pragma unroll
    for (int r=0;r<4;r++) inv[r] = 1.f/lsum[r];
    const int qbase = b*2048 + qt*128 + w*16;
#pragma unroll
    for (int n=0;n<8;n++)
#pragma unroll
      for (int r=0;r<4;r++)
        y[(size_t)(qbase + lg*4 + r)*2048 + h*128 + n*16 + lr] = f2b(yacc[n][r]*inv[r]);
  };
  loadQ(); resetAcc();

  for (int it=0; it<17; ++it){
    const int kt = (it < nA) ? it : it - nA;
    const int kb = kt*128;
    const bool diag = (kt == qt);
    if (it+1 < 17) loadt(it+1);           // reg prefetch: latency hides under compute

    // ---- QK^T : 32 MFMA ----
    f32x4 sc[8];
#pragma unroll
    for (int n=0;n<8;n++) sc[n] = f32x4{0.f,0.f,0.f,0.f};
    __builtin_amdgcn_s_setprio(1);
#pragma unroll
    for (int c=0;c<4;c++)
#pragma unroll
      for (int ng=0; ng<8; ++ng){
        const int n = ng*16 + lr;
        bf16x8 bk = *(const bf16x8*)&Kl[n*128 + (((c*4+lg) ^ (n&15))*8)];
        sc[ng] = __builtin_amdgcn_mfma_f32_16x16x32_bf16(aq[c], bk, sc[ng], 0,0,0);
      }
    __builtin_amdgcn_s_setprio(0);

    // ---- online softmax ----
    float corr[4];
#pragma unroll
    for (int r=0;r<4;r++){
      const int qg = qt*128 + w*16 + lg*4 + r;
      float vmax = -1e30f;
#pragma unroll
      for (int ng=0; ng<8; ++ng){
        float v0 = sc[ng][r]*scale;
        if (diag && (kb + ng*16 + lr) > qg) v0 = -1e30f;
        sc[ng][r] = v0;
        vmax = fmaxf(vmax, v0);
      }
#pragma unroll
      for (int mm=1; mm<16; mm<<=1) vmax = fmaxf(vmax, __shfl_xor(vmax, mm));
      const float mnew = fmaxf(mrow[r], vmax);
      corr[r] = __expf(mrow[r] - mnew);
      mrow[r] = mnew;
      float sum = 0.f;
#pragma unroll
      for (int ng=0; ng<8; ++ng){
        const float p = __expf(sc[ng][r] - mnew);
        sc[ng][r] = p; sum += p;
      }
#pragma unroll
      for (int mm=1; mm<16; mm<<=1) sum += __shfl_xor(sum, mm);
      lsum[r] = lsum[r]*corr[r] + sum;
    }
#pragma unroll
    for (int n=0;n<8;n++)
#pragma unroll
      for (int r=0;r<4;r++) yacc[n][r] *= corr[r];

    // ---- P -> LDS (per-wave), re-fragment ----
#pragma unroll
    for (int ng=0; ng<8; ++ng)
#pragma unroll
      for (int r=0;r<4;r++)
        Pl[w][lg*4+r][ng*16+lr] = f2b(sc[ng][r]);
    asm volatile("s_waitcnt lgkmcnt(0)" ::: "memory");
    __builtin_amdgcn_sched_barrier(0);    // rule 18: keep reads after the wait
    bf16x8 ap[4];
#pragma unroll
    for (int kc=0;kc<4;kc++)
      ap[kc] = *(const bf16x8*)&Pl[w][lr][kc*32 + lg*8];

    // ---- PV : 32 MFMA ----
    __builtin_amdgcn_s_setprio(1);
#pragma unroll
    for (int n=0;n<8;n++)
#pragma unroll
      for (int kc=0;kc<4;kc++){
        const int d = n*16 + lr;
        bf16x8 bv = *(const bf16x8*)&Vl[d*128 + (((kc*4+lg) ^ (d&15))*8)];
        yacc[n] = __builtin_amdgcn_mfma_f32_16x16x32_bf16(ap[kc], bv, yacc[n], 0,0,0);
      }
    __builtin_amdgcn_s_setprio(0);

    if (it == nA-1){                      // phase A done: emit, switch to qt=15-vq
      writeOut();
      qt = 15 - vq;
      loadQ(); resetAcc();
    }
    __syncthreads();                      // all waves done reading Kl/Vl
    if (it+1 < 17) writet();              // vmcnt-drained reg tiles -> LDS
    __syncthreads();
  }
  writeOut();                             // phase B output
}

// ---------------- host ----------------
extern "C" void kernel_launch(void* const* d_in, const int* in_sizes, int n_in,
                              void* d_out, int out_size, void* d_ws, size_t ws_size,
                              hipStream_t stream){
  char* ws = (char*)d_ws;
  const size_t MB = 1048576;
  uint32_t* flag = (uint32_t*)(ws);
  float* fcF = (float*)(ws + 1*MB);        // 512 KB
  float* fsF = (float*)(ws + 1*MB + 524288);
  u16* xb   = (u16*)(ws + 2*MB);           // 16 MB  (reused as yb after gemm1)
  u16* waT  = (u16*)(ws + 18*MB);          // 16 MB
  u16* wpT  = (u16*)(ws + 34*MB);          // 8 MB
  u16* qkvb = (u16*)(ws + 42*MB);          // 32 MB
  u16* vTb  = (u16*)(ws + 74*MB);          // 8 MB   -> total 82 MB
  u16* yb   = xb;                          // x dead after gemm1

  detect_k<<<1, 64, 0, stream>>>((const uint32_t*)d_in[3], flag);
  cvtf_k  <<<512, 256, 0, stream>>>(d_in[3], fcF, 131072, flag);
  cvtf_k  <<<512, 256, 0, stream>>>(d_in[4], fsF, 131072, flag);
  cvtx_k  <<<4096, 256, 0, stream>>>(d_in[0], xb, 1048576, flag);
  wtrans_k<<<dim3(64,32,1), 512, 0, stream>>>(d_in[1], waT, 4096, 2048, flag);
  wtrans_k<<<dim3(32,32,1), 512, 0, stream>>>(d_in[2], wpT, 2048, 2048, flag);
  gemm_bt <<<dim3(1024,1,1), 256, 0, stream>>>(xb, waT, qkvb, 4096, 4096, 2048, flag, 0);
  rope_k  <<<dim3(24576,1,1), 256, 0, stream>>>(qkvb, fcF, fsF);
  vtrans_k<<<dim3(2,32,16), 512, 0, stream>>>(qkvb, vTb);
  attn_k  <<<dim3(256,1,1), 512, 0, stream>>>(qkvb, vTb, yb);
  gemm_bt <<<dim3(512,1,1), 256, 0, stream>>>(yb, wpT, d_out, 4096, 2048, 2048, flag, 1);
}

// Round 5
// 303.819 us; speedup vs baseline: 1.2076x; 1.0501x over previous
//
#include <hip/hip_runtime.h>
#include <hip/hip_bf16.h>
#include <stdint.h>
#include <stddef.h>

typedef unsigned short u16;
using bf16x8 = __attribute__((ext_vector_type(8))) short;   // 8 bf16 = 4 VGPR
using f32x4  = __attribute__((ext_vector_type(4))) float;
using f32x16 = __attribute__((ext_vector_type(16))) float;

#define DEVFN static __device__ __forceinline__

DEVFN u16 f2b(float f){ __hip_bfloat16 h = __float2bfloat16(f); return *reinterpret_cast<u16*>(&h); }
DEVFN float b2f(u16 u){ __hip_bfloat16 h; *reinterpret_cast<u16*>(&h) = u; return __bfloat162float(h); }

DEVFN void gload_lds16(const void* g, void* l){
  __builtin_amdgcn_global_load_lds(
      (const __attribute__((address_space(1))) void*)g,
      (__attribute__((address_space(3))) void*)l, 16, 0, 0);
}

// ---------------- dtype detect: freqs_cos[0]==1.0f -> f32 (0x3F800000), bf16 pair -> 0x3F803F80
__global__ void detect_k(const uint32_t* __restrict__ fc_raw, uint32_t* __restrict__ flag){
  if (threadIdx.x == 0 && blockIdx.x == 0)
    flag[0] = (fc_raw[0] == 0x3F800000u) ? 1u : 0u;
}

// ---------------- freqs -> f32 table ----------------
__global__ __launch_bounds__(256) void cvtf_k(const void* __restrict__ in, float* __restrict__ out,
                                              int n, const uint32_t* __restrict__ flag){
  const int i = blockIdx.x*256 + threadIdx.x;
  if (i >= n) return;
  if (flag[0]) out[i] = ((const float*)in)[i];
  else         out[i] = b2f(((const u16*)in)[i]);
}

// ---------------- x -> bf16 (8 elems/thread) ----------------
__global__ __launch_bounds__(256) void cvtx_k(const void* __restrict__ in, u16* __restrict__ out,
                                              int n8, const uint32_t* __restrict__ flag){
  const int i = blockIdx.x*256 + threadIdx.x;
  if (i >= n8) return;
  __align__(16) u16 e[8];
  if (flag[0]){
    const float* f = (const float*)in + (size_t)i*8;
    float4 a = *(const float4*)f, b = *(const float4*)(f+4);
    e[0]=f2b(a.x); e[1]=f2b(a.y); e[2]=f2b(a.z); e[3]=f2b(a.w);
    e[4]=f2b(b.x); e[5]=f2b(b.y); e[6]=f2b(b.z); e[7]=f2b(b.w);
  } else {
    *(uint4*)e = *((const uint4*)in + i);
  }
  *(uint4*)(out + (size_t)i*8) = *(const uint4*)e;
}

// ---------------- weight transpose (+dtype cvt): in (R x C) -> out bf16 (C x R) ----------------
__global__ __launch_bounds__(512) void wtrans_k(const void* __restrict__ in, u16* __restrict__ out,
                                                int C, int R, const uint32_t* __restrict__ flag){
  __shared__ __align__(16) u16 tile[64][72];
  const int r0 = blockIdx.y*64, c0 = blockIdx.x*64;
  const int t = threadIdx.x, r = t>>3, cs = (t&7)*8;
  __align__(16) u16 e[8];
  if (flag[0]){
    const float* f = (const float*)in + (size_t)(r0+r)*C + c0 + cs;
    float4 a = *(const float4*)f, b = *(const float4*)(f+4);
    e[0]=f2b(a.x); e[1]=f2b(a.y); e[2]=f2b(a.z); e[3]=f2b(a.w);
    e[4]=f2b(b.x); e[5]=f2b(b.y); e[6]=f2b(b.z); e[7]=f2b(b.w);
  } else {
    *(uint4*)e = *(const uint4*)((const u16*)in + (size_t)(r0+r)*C + c0 + cs);
  }
#pragma unroll
  for (int j=0;j<8;j++) tile[cs+j][r] = e[j];
  __syncthreads();
  uint4 o = *(const uint4*)&tile[r][cs];
  *(uint4*)(out + (size_t)(c0+r)*R + r0 + cs) = o;
}

// ---------------- V transpose: qkv v-slice (t x d) -> vT[(b*8+g)*128 + d][t] ----------------
__global__ __launch_bounds__(512) void vtrans_k(const u16* __restrict__ qkv, u16* __restrict__ vT){
  __shared__ __align__(16) u16 tile[64][72];
  const int z = blockIdx.z, b = z>>3, g = z&7;
  const u16* in = qkv + (size_t)(b*2048)*4096 + 3072 + g*128;
  u16* out = vT + (size_t)z*128*2048;
  const int r0 = blockIdx.y*64, c0 = blockIdx.x*64;   // r0 over t, c0 over d
  const int t = threadIdx.x, r = t>>3, cs = (t&7)*8;
  uint4 v = *(const uint4*)(in + (size_t)(r0+r)*4096 + c0 + cs);
  const u16* e = (const u16*)&v;
#pragma unroll
  for (int j=0;j<8;j++) tile[cs+j][r] = e[j];
  __syncthreads();
  uint4 o = *(const uint4*)&tile[r][cs];
  *(uint4*)(out + (size_t)(c0+r)*2048 + r0 + cs) = o;
}

// ---------------- RoPE in-place on q (cols 0..2047) and k (cols 2048..3071) ----------------
__global__ __launch_bounds__(256) void rope_k(u16* qkv, const float* __restrict__ fc,
                                              const float* __restrict__ fs){
  const int idx = blockIdx.x*256 + threadIdx.x;    // 4096 rows * 1536 pairs
  const int row = idx / 1536;
  const int p   = idx % 1536;
  const int col0 = p*2;
  const int t = row & 2047;
  const int i = p & 63;
  uint32_t* ptr = (uint32_t*)(qkv + (size_t)row*4096 + col0);
  uint32_t u = *ptr;
  float x0 = b2f((u16)(u & 0xffff));
  float x1 = b2f((u16)(u >> 16));
  float c = fc[t*64+i], s = fs[t*64+i];
  float o0 = x0*c - x1*s;
  float o1 = x0*s + x1*c;
  *ptr = (uint32_t)f2b(o0) | ((uint32_t)f2b(o1) << 16);
}

// ---------------- GEMM: C(MxN) = A(MxK) * Bt(NxK)^T, bf16 in, fp32 accum ----------------
__global__ __launch_bounds__(256) void gemm_bt(const u16* __restrict__ A, const u16* __restrict__ Bt,
                                               void* __restrict__ Cv, int M, int N, int K,
                                               const uint32_t* __restrict__ flag, int fin){
  __shared__ __align__(16) u16 Al[2][128*32];
  __shared__ __align__(16) u16 Bl[2][128*32];
  const int nwg_x = N>>7;
  int wg = blockIdx.x;
  {
    const int nwg = gridDim.x;
    const int cpx = nwg >> 3;
    wg = (wg & 7)*cpx + (wg >> 3);
  }
  const int tm = (wg / nwg_x)*128, tn = (wg % nwg_x)*128;
  const int tid = threadIdx.x, w = tid>>6, l = tid&63, lr = l&15, lg = l>>4;
  const int wr = w>>1, wc = w&1;

  f32x4 acc[4][4] = {};

  auto stage = [&](int buf, int kk){
#pragma unroll
    for (int issue=0; issue<2; ++issue){
      const int c = issue*256 + w*64 + l;
      const int r = c>>2, sl = c&3;
      const int gch = sl ^ (r&3);
      gload_lds16(A  + (size_t)(tm + r)*K + kk + gch*8, &Al[buf][(issue*256 + w*64)*8]);
      gload_lds16(Bt + (size_t)(tn + r)*K + kk + gch*8, &Bl[buf][(issue*256 + w*64)*8]);
    }
  };

  stage(0, 0);
  __syncthreads();
  const int nk = K>>5;
  for (int kt=0; kt<nk; ++kt){
    if (kt+1 < nk) stage((kt+1)&1, (kt+1)*32);
    const u16* Ab = Al[kt&1];
    const u16* Bb = Bl[kt&1];
    bf16x8 a[4], b[4];
#pragma unroll
    for (int mi=0;mi<4;mi++){
      const int rr = wr*64 + mi*16 + lr;
      a[mi] = *(const bf16x8*)&Ab[rr*32 + ((lg ^ (rr&3))*8)];
    }
#pragma unroll
    for (int ni=0;ni<4;ni++){
      const int rr = wc*64 + ni*16 + lr;
      b[ni] = *(const bf16x8*)&Bb[rr*32 + ((lg ^ (rr&3))*8)];
    }
#pragma unroll
    for (int mi=0;mi<4;mi++)
#pragma unroll
      for (int ni=0;ni<4;ni++)
        acc[mi][ni] = __builtin_amdgcn_mfma_f32_16x16x32_bf16(a[mi], b[ni], acc[mi][ni], 0,0,0);
    __syncthreads();
  }
  const bool of32 = fin && (flag[0] != 0);
#pragma unroll
  for (int mi=0;mi<4;mi++)
#pragma unroll
    for (int ni=0;ni<4;ni++)
#pragma unroll
      for (int reg=0;reg<4;reg++){
        const int row = tm + wr*64 + mi*16 + lg*4 + reg;
        const int col = tn + wc*64 + ni*16 + lr;
        const size_t idx = (size_t)row*N + col;
        const float v = acc[mi][ni][reg];
        if (of32) ((float*)Cv)[idx] = v;
        else      ((u16*)Cv)[idx]   = f2b(v);
      }
}

// ---------------- causal GQA flash attention v3 ----------------
// 256 blocks (1/CU), 8 waves. Swapped-operand 32x32x16 MFMA: S^T = mfma(K, Q^T)
// puts qrow = lane&31 -> softmax is lane-local (no LDS P roundtrip, no shfl chains).
// kv-parity split: waves 0-3 even 64-col kv tiles, waves 4-7 odd tiles, same 128
// q-rows; merged flash-decoding style at phase end. Each block serially runs
// q-tiles (vq, 15-vq) -> 17 uniform steps. LDS 128KB = 2 groups x 2 dbuf x 32KB;
// ONE barrier per step. g = blockIdx&7 -> (b,g) KV slice stays XCD-local.
__global__ __launch_bounds__(512, 2) void attn_k(const u16* __restrict__ qkv,
                                                 const u16* __restrict__ vT,
                                                 u16* __restrict__ y){
  // per (buf,grp): K [64 kv][128 d] at 0..8191, V^T [128 d][64 kv] at 8192..16383
  __shared__ __align__(16) u16 KV[2][2][16384];
  const int i0 = blockIdx.x;
  const int g  = i0 & 7;
  const int r1 = i0 >> 3;
  const int hl = r1 & 1;
  const int vq = (r1 >> 1) & 7;
  const int b  = r1 >> 4;
  const int h  = g*2 + hl;

  const int tid = threadIdx.x;
  const int w = tid >> 6, l = tid & 63;
  const int grp = w >> 2, wq = w & 3;
  const int lq = l & 31;            // qrow-in-wave (S^T col) / A-frag row
  const int hi = l >> 5;
  const float scale = 0.08838834764831845f;   // 1/sqrt(128)

  const u16* kg = qkv + (size_t)(b*2048)*4096 + 2048 + g*128;
  const u16* vg = vT  + (size_t)(b*8+g)*128*2048;

  // ---- staging: all 512 threads stage both groups' next tiles (128 kv rows) ----
  const int rk = tid >> 2, cb = tid & 3;     // rk: K kv-row / V d-row (0..127)
  uint4 kpre[4], vpre[4];
  auto loadT = [&](int kvbase){
#pragma unroll
    for (int j=0;j<4;j++){
      const int ch = cb + j*4;               // 16B chunk 0..15
      kpre[j] = *(const uint4*)(kg + (size_t)(kvbase + rk)*4096 + ch*8);
      vpre[j] = *(const uint4*)(vg + (size_t)rk*2048 + kvbase + ch*8);
    }
  };
  auto writeT = [&](int buf){
    u16* Kd = &KV[buf][rk>>6][0];
    const int rl = rk & 63;
#pragma unroll
    for (int j=0;j<4;j++){
      const int ch = cb + j*4;
      *(uint4*)&Kd[rl*128 + ((ch ^ (rl&15))*8)] = kpre[j];
    }
#pragma unroll
    for (int j=0;j<4;j++){
      const int ch = cb + j*4;               // kv chunk: group = ch>>3
      u16* Vd = &KV[buf][ch>>3][8192];
      *(uint4*)&Vd[rk*64 + (((ch&7) ^ (rk&7))*8)] = vpre[j];
    }
  };

  int qt = vq;
  const int nA = vq + 1;                     // steps in phase A; total 17
  bf16x8 qf[8];
  f32x16 yacc[4];
  float mrow, lsum;

  auto loadQ = [&]{
    const size_t qrow = (size_t)(b*2048 + qt*128 + wq*32 + lq);
    const u16* qp = qkv + qrow*4096 + h*128 + hi*8;
#pragma unroll
    for (int ds=0; ds<8; ++ds) qf[ds] = *(const bf16x8*)(qp + ds*16);
  };
  auto resetAcc = [&]{
#pragma unroll
    for (int dt=0; dt<4; ++dt)
#pragma unroll
      for (int r=0; r<16; ++r) yacc[dt][r] = 0.f;
    mrow = -1e30f; lsum = 0.f;
  };

  // flash-decoding merge of the two parity groups + coalesced store, at phase end.
  auto mergePhase = [&](u16* Mb){
    float* Mm = (float*)Mb; float* Ml = Mm + 128;
    u16* MOs = Mb + 512 + wq*4096;           // slot: [32 q][128 d] bf16, XOR-swz
    __syncthreads();
    if (grp == 1){
      if (l < 32){ Mm[wq*32 + l] = mrow; Ml[wq*32 + l] = lsum; }
#pragma unroll
      for (int dt=0; dt<4; ++dt)
#pragma unroll
        for (int rq=0; rq<4; ++rq){
          const int d0 = dt*32 + rq*8 + hi*4;
          uint32_t lo = (uint32_t)f2b(yacc[dt][rq*4+0]) | ((uint32_t)f2b(yacc[dt][rq*4+1])<<16);
          uint32_t hi2= (uint32_t)f2b(yacc[dt][rq*4+2]) | ((uint32_t)f2b(yacc[dt][rq*4+3])<<16);
          const int idx = (lq*128 + d0) ^ ((lq&7)<<3);
          *(uint2*)&MOs[idx] = make_uint2(lo, hi2);
        }
    }
    __syncthreads();
    if (grp == 0){
      const float mo = Mm[wq*32 + lq], lo_ = Ml[wq*32 + lq];
      const float ms = fmaxf(mrow, mo);
      const float ce = __expf(mrow - ms), co = __expf(mo - ms);
      const float inv = 1.f / (lsum*ce + lo_*co);
#pragma unroll
      for (int dt=0; dt<4; ++dt)
#pragma unroll
        for (int rq=0; rq<4; ++rq){
          const int d0 = dt*32 + rq*8 + hi*4;
          const int idx = (lq*128 + d0) ^ ((lq&7)<<3);
          uint2 pr = *(const uint2*)&MOs[idx];
          const float yo0 = b2f((u16)(pr.x & 0xffff)), yo1 = b2f((u16)(pr.x >> 16));
          const float yo2 = b2f((u16)(pr.y & 0xffff)), yo3 = b2f((u16)(pr.y >> 16));
          const float f0 = (yacc[dt][rq*4+0]*ce + yo0*co)*inv;
          const float f1 = (yacc[dt][rq*4+1]*ce + yo1*co)*inv;
          const float f2v= (yacc[dt][rq*4+2]*ce + yo2*co)*inv;
          const float f3 = (yacc[dt][rq*4+3]*ce + yo3*co)*inv;
          uint32_t lo = (uint32_t)f2b(f0) | ((uint32_t)f2b(f1)<<16);
          uint32_t hi2= (uint32_t)f2b(f2v)| ((uint32_t)f2b(f3)<<16);
          *(uint2*)&MOs[idx] = make_uint2(lo, hi2);
        }
    }
    __syncthreads();
    // cooperative coalesced store: wave pair splits 32 rows of its slot
    const int qb2 = b*2048 + qt*128 + wq*32;
#pragma unroll
    for (int p=0; p<2; ++p){
      const int row = grp*16 + p*8 + (l>>3);
      const int gc = l & 7;
      const int idx0 = (row*128 + gc*16) ^ ((row&7)<<3);
      const int idx1 = (row*128 + gc*16 + 8) ^ ((row&7)<<3);
      uint4 v0 = *(const uint4*)&MOs[idx0];
      uint4 v1 = *(const uint4*)&MOs[idx1];
      u16* yp = y + (size_t)(qb2 + row)*2048 + h*128 + gc*16;
      *(uint4*)yp = v0;
      *(uint4*)(yp + 8) = v1;
    }
    __syncthreads();
  };

  loadT(0); writeT(0); __syncthreads();
  loadQ(); resetAcc();

  for (int s=0; s<17; ++s){
    if (s == nA){                            // phase A done: merge+store, switch q-tile
      mergePhase(&KV[(nA&1)^1][0][0]);
      qt = 15 - vq;
      loadQ(); resetAcc();
    }
    const int sj = (s < nA) ? s : s - nA;
    const int kvbase = sj*128;
    if (s+1 < 17){
      const int s2 = s+1;
      const int sj2 = (s2 < nA) ? s2 : s2 - nA;
      loadT(sj2*128);                        // reg prefetch, lands under compute
    }
    const u16* Kb = &KV[s&1][grp][0];
    const u16* Vb = Kb + 8192;
    const int tilebase = kvbase + grp*64;
    const int qmin = qt*128 + wq*32;
    const int qrow = qmin + lq;

    if (tilebase <= qmin + 31){              // wave-uniform: any unmasked work?
      // ---- S^T = K * Q^T : 16 MFMA 32x32x16 ----
      f32x16 sc[2];
#pragma unroll
      for (int t=0;t<2;t++)
#pragma unroll
        for (int r=0;r<16;r++) sc[t][r] = 0.f;
      __builtin_amdgcn_s_setprio(1);
#pragma unroll
      for (int t=0; t<2; ++t){
        const int r = t*32 + lq;
        const int rsw = r & 15;
#pragma unroll
        for (int ds=0; ds<8; ++ds){
          const bf16x8 kf = *(const bf16x8*)&Kb[r*128 + (((2*ds+hi) ^ rsw)*8)];
          sc[t] = __builtin_amdgcn_mfma_f32_32x32x16_bf16(kf, qf[ds], sc[t], 0,0,0);
        }
      }
      __builtin_amdgcn_s_setprio(0);

      // ---- lane-local online softmax (kpos = (r&3)+8*(r>>2)+4*hi + 32*t) ----
      const bool needmask = (tilebase + 63) > qmin;
      float pmax = -1e30f;
#pragma unroll
      for (int t=0;t<2;t++)
#pragma unroll
        for (int r=0;r<16;r++){
          float v = sc[t][r]*scale;
          if (needmask){
            const int kp = tilebase + t*32 + (r&3) + 8*(r>>2) + 4*hi;
            if (kp > qrow) v = -1e30f;
          }
          sc[t][r] = v;
          pmax = fmaxf(pmax, v);
        }
      pmax = fmaxf(pmax, __shfl_xor(pmax, 32));
      if (!__all(pmax <= mrow + 8.f)){       // T13 defer-max
        const float mnew = fmaxf(mrow, pmax);
        const float corr = __expf(mrow - mnew);
        mrow = mnew; lsum *= corr;
#pragma unroll
        for (int dt=0;dt<4;dt++)
#pragma unroll
          for (int r=0;r<16;r++) yacc[dt][r] *= corr;
      }
      float lsub = 0.f;
#pragma unroll
      for (int t=0;t<2;t++)
#pragma unroll
        for (int r=0;r<16;r++){
          const float p = __expf(sc[t][r] - mrow);
          sc[t][r] = p; lsub += p;
        }
      lsub += __shfl_xor(lsub, 32);
      lsum += lsub;

      // ---- P -> PV B-fragments (pack + half-wave exchange) ----
      __align__(16) uint32_t pw[4][4];       // [ks][word]
#pragma unroll
      for (int t=0;t<2;t++)
#pragma unroll
        for (int half=0; half<2; ++half){
          const int q8 = half*8;
          uint32_t X0 = (uint32_t)f2b(sc[t][q8+0]) | ((uint32_t)f2b(sc[t][q8+1])<<16);
          uint32_t X1 = (uint32_t)f2b(sc[t][q8+2]) | ((uint32_t)f2b(sc[t][q8+3])<<16);
          uint32_t X2 = (uint32_t)f2b(sc[t][q8+4]) | ((uint32_t)f2b(sc[t][q8+5])<<16);
          uint32_t X3 = (uint32_t)f2b(sc[t][q8+6]) | ((uint32_t)f2b(sc[t][q8+7])<<16);
          const uint32_t pX0 = (uint32_t)__shfl_xor((int)X0, 32);
          const uint32_t pX1 = (uint32_t)__shfl_xor((int)X1, 32);
          const uint32_t pX2 = (uint32_t)__shfl_xor((int)X2, 32);
          const uint32_t pX3 = (uint32_t)__shfl_xor((int)X3, 32);
          const int ks = t*2 + half;
          pw[ks][0] = hi ? pX2 : X0;
          pw[ks][1] = hi ? pX3 : X1;
          pw[ks][2] = hi ? X2 : pX0;
          pw[ks][3] = hi ? X3 : pX1;
        }

      // ---- O^T += V^T * P^T : 16 MFMA 32x32x16 ----
      __builtin_amdgcn_s_setprio(1);
#pragma unroll
      for (int dt=0; dt<4; ++dt){
        const int d = dt*32 + lq;
        const int dsw = d & 7;
#pragma unroll
        for (int ks=0; ks<4; ++ks){
          const bf16x8 vf = *(const bf16x8*)&Vb[8192 - 8192 + d*64 + (((2*ks+hi) ^ dsw)*8)];
          yacc[dt] = __builtin_amdgcn_mfma_f32_32x32x16_bf16(vf, *(const bf16x8*)&pw[ks][0], yacc[dt], 0,0,0);
        }
      }
      __builtin_amdgcn_s_setprio(0);
    }

    if (s+1 < 17) writeT((s&1)^1);           // write next tile into other buffer
    __syncthreads();                         // ONE barrier per step
  }
  mergePhase(&KV[0][0][0]);                  // phase B merge+store
}

// ---------------- host ----------------
extern "C" void kernel_launch(void* const* d_in, const int* in_sizes, int n_in,
                              void* d_out, int out_size, void* d_ws, size_t ws_size,
                              hipStream_t stream){
  char* ws = (char*)d_ws;
  const size_t MB = 1048576;
  uint32_t* flag = (uint32_t*)(ws);
  float* fcF = (float*)(ws + 1*MB);
  float* fsF = (float*)(ws + 1*MB + 524288);
  u16* xb   = (u16*)(ws + 2*MB);           // 16 MB (reused as yb after gemm1)
  u16* waT  = (u16*)(ws + 18*MB);          // 16 MB
  u16* wpT  = (u16*)(ws + 34*MB);          // 8 MB
  u16* qkvb = (u16*)(ws + 42*MB);          // 32 MB
  u16* vTb  = (u16*)(ws + 74*MB);          // 8 MB
  u16* yb   = xb;

  detect_k<<<1, 64, 0, stream>>>((const uint32_t*)d_in[3], flag);
  cvtf_k  <<<512, 256, 0, stream>>>(d_in[3], fcF, 131072, flag);
  cvtf_k  <<<512, 256, 0, stream>>>(d_in[4], fsF, 131072, flag);
  cvtx_k  <<<4096, 256, 0, stream>>>(d_in[0], xb, 1048576, flag);
  wtrans_k<<<dim3(64,32,1), 512, 0, stream>>>(d_in[1], waT, 4096, 2048, flag);
  wtrans_k<<<dim3(32,32,1), 512, 0, stream>>>(d_in[2], wpT, 2048, 2048, flag);
  gemm_bt <<<dim3(1024,1,1), 256, 0, stream>>>(xb, waT, qkvb, 4096, 4096, 2048, flag, 0);
  rope_k  <<<dim3(24576,1,1), 256, 0, stream>>>(qkvb, fcF, fsF);
  vtrans_k<<<dim3(2,32,16), 512, 0, stream>>>(qkvb, vTb);
  attn_k  <<<dim3(256,1,1), 512, 0, stream>>>(qkvb, vTb, yb);
  gemm_bt <<<dim3(512,1,1), 256, 0, stream>>>(yb, wpT, d_out, 4096, 2048, 2048, flag, 1);
}